// Round 1
// baseline (151.425 us; speedup 1.0000x reference)
//
#include <hip/hip_runtime.h>
#include <hip/hip_bf16.h>

// MSA: B=8, S=1024, H=16, D=64. hidden = 1024.
// Plan: kernel 1 projects QKV to bf16 workspace (q pre-scaled by log2e/sqrt(D),
// V stored transposed per (b,h)); kernel 2 is flash-attention with
// 16x16x32 bf16 MFMA, online softmax in f32.

typedef __attribute__((ext_vector_type(8))) short short8;
typedef __attribute__((ext_vector_type(4))) float f32x4;
typedef __attribute__((ext_vector_type(4))) unsigned short u16x4;

#define MFMA16 __builtin_amdgcn_mfma_f32_16x16x32_bf16

// log2(e) / sqrt(64)
#define QSCALE 0.1803368801111204f

__device__ __forceinline__ unsigned short f2bf(float f) {
  unsigned u = __builtin_bit_cast(unsigned, f);
  u += 0x7FFFu + ((u >> 16) & 1u);   // round-to-nearest-even
  return (unsigned short)(u >> 16);
}

// ---------------- QKV projection ----------------
// grid: (B*S/64) * H = 128*16 = 2048 blocks, 256 threads.
// Block (t, h): tokens t*64..t*64+63, head h.
// q_ws/k_ws: [b*16+h][s][64] bf16 ; vt_ws: [b*16+h][d][s] bf16.
__global__ __launch_bounds__(256) void qkv_proj_kernel(
    const float* __restrict__ x,
    const float* __restrict__ Wq, const float* __restrict__ bq,
    const float* __restrict__ Wk, const float* __restrict__ bk,
    const float* __restrict__ Wv, const float* __restrict__ bv,
    unsigned short* __restrict__ q_ws,
    unsigned short* __restrict__ k_ws,
    unsigned short* __restrict__ vt_ws)
{
  __shared__ unsigned short x_lds[64][72];      // +8 pad: bank-balanced b128
  __shared__ unsigned short w_lds[3][64][72];

  const int h    = blockIdx.x & 15;
  const int t    = blockIdx.x >> 4;
  const int tid  = threadIdx.x;
  const int lane = tid & 63;
  const int wv   = tid >> 6;
  const int g    = lane >> 4;
  const int cc   = lane & 15;

  { // stage x tile + 3 weight tiles, f32 -> bf16
    const int i  = tid >> 2;        // row 0..63
    const int q4 = tid & 3;         // 16-col quarter
    const float* xs  = x  + (size_t)(t * 64 + i) * 1024 + h * 64 + q4 * 16;
    const float* wsq = Wq + (size_t)h * 4096 + i * 64 + q4 * 16;
    const float* wsk = Wk + (size_t)h * 4096 + i * 64 + q4 * 16;
    const float* wsv = Wv + (size_t)h * 4096 + i * 64 + q4 * 16;
#pragma unroll
    for (int it = 0; it < 4; ++it) {
      const int c = q4 * 16 + it * 4;
      f32x4 v; u16x4 pk;
      v = *(const f32x4*)(xs + it * 4);
#pragma unroll
      for (int j = 0; j < 4; ++j) pk[j] = f2bf(v[j]);
      *(u16x4*)&x_lds[i][c] = pk;
      v = *(const f32x4*)(wsq + it * 4);
#pragma unroll
      for (int j = 0; j < 4; ++j) pk[j] = f2bf(v[j]);
      *(u16x4*)&w_lds[0][i][c] = pk;
      v = *(const f32x4*)(wsk + it * 4);
#pragma unroll
      for (int j = 0; j < 4; ++j) pk[j] = f2bf(v[j]);
      *(u16x4*)&w_lds[1][i][c] = pk;
      v = *(const f32x4*)(wsv + it * 4);
#pragma unroll
      for (int j = 0; j < 4; ++j) pk[j] = f2bf(v[j]);
      *(u16x4*)&w_lds[2][i][c] = pk;
    }
  }
  __syncthreads();

  f32x4 aq[4], ak[4], av[4];
#pragma unroll
  for (int f = 0; f < 4; ++f) {
    aq[f] = (f32x4){0.f, 0.f, 0.f, 0.f};
    ak[f] = (f32x4){0.f, 0.f, 0.f, 0.f};
    av[f] = (f32x4){0.f, 0.f, 0.f, 0.f};
  }

  const int arow = wv * 16 + cc;   // token row for A fragment
  const int kc   = g * 8;          // k-offset within 32-wide K step
#pragma unroll
  for (int kk = 0; kk < 2; ++kk) {
    short8 a = *(const short8*)&x_lds[arow][kk * 32 + kc];
#pragma unroll
    for (int f = 0; f < 4; ++f) {
      const int br = f * 16 + cc;  // e row of W (N index)
      aq[f] = MFMA16(a, *(const short8*)&w_lds[0][br][kk * 32 + kc], aq[f], 0, 0, 0);
      ak[f] = MFMA16(a, *(const short8*)&w_lds[1][br][kk * 32 + kc], ak[f], 0, 0, 0);
      av[f] = MFMA16(a, *(const short8*)&w_lds[2][br][kk * 32 + kc], av[f], 0, 0, 0);
    }
  }

  // epilogue: C/D layout col = lane&15 (e), row = (lane>>4)*4 + r (token)
  const int b  = t >> 4;
  const int s0 = (t & 15) << 6;
  const size_t base = ((size_t)(b * 16 + h)) << 16;   // *S*D = 65536
#pragma unroll
  for (int f = 0; f < 4; ++f) {
    const int e = f * 16 + cc;
    const float bqv = bq[h * 64 + e];
    const float bkv = bk[h * 64 + e];
    const float bvv = bv[h * 64 + e];
#pragma unroll
    for (int r = 0; r < 4; ++r) {
      const int sl = s0 + wv * 16 + g * 4 + r;
      q_ws[base + ((size_t)sl << 6) + e]        = f2bf((aq[f][r] + bqv) * QSCALE);
      k_ws[base + ((size_t)sl << 6) + e]        = f2bf(ak[f][r] + bkv);
      vt_ws[base + ((size_t)e << 10) + sl]      = f2bf(av[f][r] + bvv);
    }
  }
}

// ---------------- flash attention ----------------
// grid: B*H*(S/64) = 2048 blocks, 256 threads (4 waves x 16 q-rows).
__global__ __launch_bounds__(256) void attn_kernel(
    const unsigned short* __restrict__ q_ws,
    const unsigned short* __restrict__ k_ws,
    const unsigned short* __restrict__ vt_ws,
    float* __restrict__ out)
{
  __shared__ unsigned short K_lds[64][72];    // [key][d]
  __shared__ unsigned short VT_lds[64][72];   // [d][key]
  __shared__ unsigned short P_lds[4][16][72]; // per wave [q][key]

  const int qt   = blockIdx.x & 15;
  const int bh   = blockIdx.x >> 4;
  const int b    = bh >> 4;
  const int h    = bh & 15;
  const size_t base = (size_t)bh << 16;
  const int tid  = threadIdx.x;
  const int lane = tid & 63;
  const int wv   = tid >> 6;
  const int g    = lane >> 4;
  const int cc   = lane & 15;

  // Q fragments: A layout row = lane&15, k = (lane>>4)*8 + j
  short8 qf[2];
  {
    const unsigned short* qp =
        q_ws + base + ((size_t)(qt * 64 + wv * 16 + cc) << 6) + g * 8;
    qf[0] = *(const short8*)qp;
    qf[1] = *(const short8*)(qp + 32);
  }

  f32x4 o[4];
#pragma unroll
  for (int f = 0; f < 4; ++f) o[f] = (f32x4){0.f, 0.f, 0.f, 0.f};
  float m[4], lsum[4];
#pragma unroll
  for (int r = 0; r < 4; ++r) { m[r] = -1e30f; lsum[r] = 0.f; }

  const int srow = tid >> 3;        // staging row 0..31
  const int scol = (tid & 7) * 8;   // staging col (elements)

  for (int kv = 0; kv < 16; ++kv) {
    __syncthreads();
#pragma unroll
    for (int half = 0; half < 2; ++half) {
      const int r0 = srow + half * 32;
      *(short8*)&K_lds[r0][scol] =
          *(const short8*)(k_ws + base + ((size_t)(kv * 64 + r0) << 6) + scol);
      *(short8*)&VT_lds[r0][scol] =
          *(const short8*)(vt_ws + base + ((size_t)r0 << 10) + kv * 64 + scol);
    }
    __syncthreads();

    // S = Q K^T (in log2 units; q pre-scaled)
    f32x4 s[4];
#pragma unroll
    for (int f = 0; f < 4; ++f) s[f] = (f32x4){0.f, 0.f, 0.f, 0.f};
#pragma unroll
    for (int kk = 0; kk < 2; ++kk) {
#pragma unroll
      for (int f = 0; f < 4; ++f) {
        s[f] = MFMA16(qf[kk],
                      *(const short8*)&K_lds[f * 16 + cc][kk * 32 + g * 8],
                      s[f], 0, 0, 0);
      }
    }

    // online softmax; lane holds key = f*16+cc for q-row = g*4+r
    float mx[4];
#pragma unroll
    for (int r = 0; r < 4; ++r)
      mx[r] = fmaxf(fmaxf(s[0][r], s[1][r]), fmaxf(s[2][r], s[3][r]));
#pragma unroll
    for (int off = 1; off <= 8; off <<= 1)
#pragma unroll
      for (int r = 0; r < 4; ++r)
        mx[r] = fmaxf(mx[r], __shfl_xor(mx[r], off, 64));
    float sc[4];
#pragma unroll
    for (int r = 0; r < 4; ++r) {
      const float mn = fmaxf(m[r], mx[r]);
      sc[r] = exp2f(m[r] - mn);
      m[r] = mn;
    }
    float ps[4] = {0.f, 0.f, 0.f, 0.f};
    unsigned short pb[4][4];
#pragma unroll
    for (int f = 0; f < 4; ++f)
#pragma unroll
      for (int r = 0; r < 4; ++r) {
        const float p = exp2f(s[f][r] - m[r]);
        ps[r] += p;
        pb[f][r] = f2bf(p);
      }
#pragma unroll
    for (int off = 1; off <= 8; off <<= 1)
#pragma unroll
      for (int r = 0; r < 4; ++r)
        ps[r] += __shfl_xor(ps[r], off, 64);
#pragma unroll
    for (int r = 0; r < 4; ++r) lsum[r] = lsum[r] * sc[r] + ps[r];
#pragma unroll
    for (int f = 0; f < 4; ++f)
#pragma unroll
      for (int r = 0; r < 4; ++r) o[f][r] *= sc[r];

    // P -> wave-private LDS (bf16); same-wave ds ordering, no barrier needed
#pragma unroll
    for (int f = 0; f < 4; ++f)
#pragma unroll
      for (int r = 0; r < 4; ++r)
        P_lds[wv][g * 4 + r][f * 16 + cc] = pb[f][r];

    // O += P V
#pragma unroll
    for (int kk2 = 0; kk2 < 2; ++kk2) {
      short8 pa = *(const short8*)&P_lds[wv][cc][kk2 * 32 + g * 8];
#pragma unroll
      for (int of = 0; of < 4; ++of) {
        o[of] = MFMA16(pa,
                       *(const short8*)&VT_lds[of * 16 + cc][kk2 * 32 + g * 8],
                       o[of], 0, 0, 0);
      }
    }
  }

  // normalize + store f32: out[b][s][h*64+e]
  float inv[4];
#pragma unroll
  for (int r = 0; r < 4; ++r) inv[r] = 1.0f / lsum[r];
  const int sbase = qt * 64 + wv * 16 + g * 4;
#pragma unroll
  for (int of = 0; of < 4; ++of)
#pragma unroll
    for (int r = 0; r < 4; ++r)
      out[((size_t)b << 20) + ((size_t)(sbase + r) << 10) + h * 64 + of * 16 + cc]
          = o[of][r] * inv[r];
}

extern "C" void kernel_launch(void* const* d_in, const int* in_sizes, int n_in,
                              void* d_out, int out_size, void* d_ws, size_t ws_size,
                              hipStream_t stream) {
  const float* x  = (const float*)d_in[0];
  const float* Wq = (const float*)d_in[1];
  const float* bq = (const float*)d_in[2];
  const float* Wk = (const float*)d_in[3];
  const float* bk = (const float*)d_in[4];
  const float* Wv = (const float*)d_in[5];
  const float* bv = (const float*)d_in[6];
  float* out = (float*)d_out;

  // workspace: 3 x 16 MB bf16 (q, k, v^T)
  unsigned short* q_ws  = (unsigned short*)d_ws;
  unsigned short* k_ws  = q_ws + (size_t)8388608;
  unsigned short* vt_ws = k_ws + (size_t)8388608;

  qkv_proj_kernel<<<2048, 256, 0, stream>>>(x, Wq, bq, Wk, bk, Wv, bv,
                                            q_ws, k_ws, vt_ws);
  attn_kernel<<<2048, 256, 0, stream>>>(q_ws, k_ws, vt_ws, out);
}

// Round 2
// 93.337 us; speedup vs baseline: 1.6223x; 1.6223x over previous
//
#include <hip/hip_runtime.h>
#include <hip/hip_bf16.h>

// MSA: B=8, S=1024, H=16, D=64.
// K1: QKV projection -> bf16 ws (q pre-scaled by log2e/sqrt(D); V^T per (b,h)).
// K2: flash attention, 32x32x16 bf16 MFMA, swapped QK^T (S^T = K Q^T) so the
//     softmax row is lane-local; P->bf16 via v_cvt_pk_bf16_f32 + permlane32_swap;
//     PV transposed (O^T = V^T P^T); frag-layout LDS tiles (conflict-free reads).

typedef __attribute__((ext_vector_type(8))) short short8;
typedef __attribute__((ext_vector_type(4))) float f32x4;
typedef __attribute__((ext_vector_type(16))) float f32x16;
typedef __attribute__((ext_vector_type(4))) unsigned short u16x4;
typedef __attribute__((ext_vector_type(4))) unsigned int u32x4;

#define MFMA16 __builtin_amdgcn_mfma_f32_16x16x32_bf16
#define MFMA32 __builtin_amdgcn_mfma_f32_32x32x16_bf16

// log2(e) / sqrt(64)
#define QSCALE 0.1803368801111204f

__device__ __forceinline__ unsigned short f2bf(float f) {
  unsigned u = __builtin_bit_cast(unsigned, f);
  u += 0x7FFFu + ((u >> 16) & 1u);   // RNE
  return (unsigned short)(u >> 16);
}

__device__ __forceinline__ unsigned cvt_pk(float lo, float hi) {
  unsigned r;
  asm("v_cvt_pk_bf16_f32 %0, %1, %2" : "=v"(r) : "v"(lo), "v"(hi));
  return r;
}
// swaps a[32+i] <-> b[i] (a.hi half with b.lo half)
__device__ __forceinline__ void pl32_swap(unsigned &a, unsigned &b) {
  asm("v_permlane32_swap_b32 %0, %1" : "+v"(a), "+v"(b));
}

// ---------------- QKV projection (unchanged from R1) ----------------
__global__ __launch_bounds__(256) void qkv_proj_kernel(
    const float* __restrict__ x,
    const float* __restrict__ Wq, const float* __restrict__ bq,
    const float* __restrict__ Wk, const float* __restrict__ bk,
    const float* __restrict__ Wv, const float* __restrict__ bv,
    unsigned short* __restrict__ q_ws,
    unsigned short* __restrict__ k_ws,
    unsigned short* __restrict__ vt_ws)
{
  __shared__ unsigned short x_lds[64][72];
  __shared__ unsigned short w_lds[3][64][72];

  const int h    = blockIdx.x & 15;
  const int t    = blockIdx.x >> 4;
  const int tid  = threadIdx.x;
  const int lane = tid & 63;
  const int wv   = tid >> 6;
  const int g    = lane >> 4;
  const int cc   = lane & 15;

  {
    const int i  = tid >> 2;
    const int q4 = tid & 3;
    const float* xs  = x  + (size_t)(t * 64 + i) * 1024 + h * 64 + q4 * 16;
    const float* wsq = Wq + (size_t)h * 4096 + i * 64 + q4 * 16;
    const float* wsk = Wk + (size_t)h * 4096 + i * 64 + q4 * 16;
    const float* wsv = Wv + (size_t)h * 4096 + i * 64 + q4 * 16;
#pragma unroll
    for (int it = 0; it < 4; ++it) {
      const int c = q4 * 16 + it * 4;
      f32x4 v; u16x4 pk;
      v = *(const f32x4*)(xs + it * 4);
#pragma unroll
      for (int j = 0; j < 4; ++j) pk[j] = f2bf(v[j]);
      *(u16x4*)&x_lds[i][c] = pk;
      v = *(const f32x4*)(wsq + it * 4);
#pragma unroll
      for (int j = 0; j < 4; ++j) pk[j] = f2bf(v[j]);
      *(u16x4*)&w_lds[0][i][c] = pk;
      v = *(const f32x4*)(wsk + it * 4);
#pragma unroll
      for (int j = 0; j < 4; ++j) pk[j] = f2bf(v[j]);
      *(u16x4*)&w_lds[1][i][c] = pk;
      v = *(const f32x4*)(wsv + it * 4);
#pragma unroll
      for (int j = 0; j < 4; ++j) pk[j] = f2bf(v[j]);
      *(u16x4*)&w_lds[2][i][c] = pk;
    }
  }
  __syncthreads();

  f32x4 aq[4], ak[4], av[4];
#pragma unroll
  for (int f = 0; f < 4; ++f) {
    aq[f] = (f32x4){0.f, 0.f, 0.f, 0.f};
    ak[f] = (f32x4){0.f, 0.f, 0.f, 0.f};
    av[f] = (f32x4){0.f, 0.f, 0.f, 0.f};
  }

  const int arow = wv * 16 + cc;
  const int kc   = g * 8;
#pragma unroll
  for (int kk = 0; kk < 2; ++kk) {
    short8 a = *(const short8*)&x_lds[arow][kk * 32 + kc];
#pragma unroll
    for (int f = 0; f < 4; ++f) {
      const int br = f * 16 + cc;
      aq[f] = MFMA16(a, *(const short8*)&w_lds[0][br][kk * 32 + kc], aq[f], 0, 0, 0);
      ak[f] = MFMA16(a, *(const short8*)&w_lds[1][br][kk * 32 + kc], ak[f], 0, 0, 0);
      av[f] = MFMA16(a, *(const short8*)&w_lds[2][br][kk * 32 + kc], av[f], 0, 0, 0);
    }
  }

  const int b  = t >> 4;
  const int s0 = (t & 15) << 6;
  const size_t base = ((size_t)(b * 16 + h)) << 16;
#pragma unroll
  for (int f = 0; f < 4; ++f) {
    const int e = f * 16 + cc;
    const float bqv = bq[h * 64 + e];
    const float bkv = bk[h * 64 + e];
    const float bvv = bv[h * 64 + e];
#pragma unroll
    for (int r = 0; r < 4; ++r) {
      const int sl = s0 + wv * 16 + g * 4 + r;
      q_ws[base + ((size_t)sl << 6) + e]   = f2bf((aq[f][r] + bqv) * QSCALE);
      k_ws[base + ((size_t)sl << 6) + e]   = f2bf(ak[f][r] + bkv);
      vt_ws[base + ((size_t)e << 10) + sl] = f2bf(av[f][r] + bvv);
    }
  }
}

// ---------------- flash attention, 8-wave-style 32x32 structure ----------------
// grid: B*H*(S/128) = 1024 blocks, 256 threads = 4 waves; QBLK=32/wave, KVBLK=64.
__global__ __launch_bounds__(256) void attn_kernel(
    const unsigned short* __restrict__ q_ws,
    const unsigned short* __restrict__ k_ws,
    const unsigned short* __restrict__ vt_ws,
    float* __restrict__ out)
{
  // frag-layout tiles: KF [0, 8KB), VF [8KB, 16KB). slot = c*128 + d2*64 + lane,
  // swizzled slot' = slot ^ ((slot>>5)&7); element = 16B (one lane's b128 frag).
  __shared__ unsigned short tiles[8192];
  char* lds = (char*)tiles;

  // XCD-bijective swizzle: 1024 blocks = 8 XCDs x 128, group same (b,h) per XCD
  const int logical = (blockIdx.x & 7) * 128 + (blockIdx.x >> 3);
  const int qt = logical & 7;
  const int bh = logical >> 3;
  const int b  = bh >> 4;
  const int h  = bh & 15;
  const size_t base = (size_t)bh << 16;   // * S*D

  const int tid = threadIdx.x;
  const int w   = tid >> 6;
  const int l   = tid & 63;
  const int hi  = l >> 5;
  const int cc  = l & 31;

  // Q fragments (B operand of S^T = K.Q^T): q-row = cc, d = c*16 + hi*8 + j
  short8 qf[4];
  {
    const unsigned short* qp =
        q_ws + base + (size_t)(qt * 128 + w * 32 + cc) * 64 + hi * 8;
    qf[0] = *(const short8*)(qp);
    qf[1] = *(const short8*)(qp + 16);
    qf[2] = *(const short8*)(qp + 32);
    qf[3] = *(const short8*)(qp + 48);
  }

  // LDS read offsets (conflict-free: per-lane consecutive 16B slots)
  int roff[4][2];
#pragma unroll
  for (int c = 0; c < 4; ++c)
#pragma unroll
    for (int d2 = 0; d2 < 2; ++d2) {
      int slot = c * 128 + d2 * 64 + l;
      roff[c][d2] = (slot ^ ((slot >> 5) & 7)) * 16;
    }

  // staging: thread (w,l), seg = w*2+it covers d/key byte-segment seg*16B
  int wboff[2];
  const unsigned short* kgp[2];
  const unsigned short* vgp[2];
#pragma unroll
  for (int it = 0; it < 2; ++it) {
    const int seg = w * 2 + it;
    int slot = (seg >> 1) * 128 + (l >> 5) * 64 + (seg & 1) * 32 + (l & 31);
    wboff[it] = (slot ^ ((slot >> 5) & 7)) * 16;
    kgp[it] = k_ws + base + (size_t)l * 64 + seg * 8;    // + kv*4096 per tile
    vgp[it] = vt_ws + base + (size_t)l * 1024 + seg * 8; // + kv*64 per tile
  }

  f32x16 ot0 = {}; f32x16 ot1 = {};   // O^T: d-tiles 0-31 / 32-63, q = cc
  float m = -1e30f, lsum = 0.f;

  short8 stK[2], stV[2];
#pragma unroll
  for (int it = 0; it < 2; ++it) {    // prefetch tile 0
    stK[it] = *(const short8*)(kgp[it]);
    stV[it] = *(const short8*)(vgp[it]);
  }

  for (int kv = 0; kv < 16; ++kv) {
    __syncthreads();                  // prior tile fully consumed
#pragma unroll
    for (int it = 0; it < 2; ++it) {
      *(short8*)(lds + wboff[it])        = stK[it];
      *(short8*)(lds + 8192 + wboff[it]) = stV[it];
    }
    __syncthreads();
    if (kv < 15) {                    // async prefetch next tile into regs
#pragma unroll
      for (int it = 0; it < 2; ++it) {
        stK[it] = *(const short8*)(kgp[it] + (size_t)(kv + 1) * 4096);
        stV[it] = *(const short8*)(vgp[it] + (size_t)(kv + 1) * 64);
      }
    }

    // ---- S^T = K Q^T (log2 units; q pre-scaled) ----
    f32x16 s0 = {}; f32x16 s1 = {};
#pragma unroll
    for (int c = 0; c < 4; ++c) {
      short8 a0 = *(const short8*)(lds + roff[c][0]);
      s0 = MFMA32(a0, qf[c], s0, 0, 0, 0);
      short8 a1 = *(const short8*)(lds + roff[c][1]);
      s1 = MFMA32(a1, qf[c], s1, 0, 0, 0);
    }

    // ---- online softmax: row q=cc is {this lane} U {lane^32} ----
    float mx = fmaxf(s0[0], s0[1]);
#pragma unroll
    for (int i = 2; i < 16; ++i) mx = fmaxf(mx, s0[i]);
#pragma unroll
    for (int i = 0; i < 16; ++i) mx = fmaxf(mx, s1[i]);
    mx = fmaxf(mx, __shfl_xor(mx, 32, 64));
    const float mn = fmaxf(m, mx);
    const float sc = __builtin_amdgcn_exp2f(m - mn);
    m = mn;

    float ps = 0.f;
#pragma unroll
    for (int i = 0; i < 16; ++i) { s0[i] = __builtin_amdgcn_exp2f(s0[i] - m); ps += s0[i]; }
#pragma unroll
    for (int i = 0; i < 16; ++i) { s1[i] = __builtin_amdgcn_exp2f(s1[i] - m); ps += s1[i]; }
    lsum = lsum * sc + ps;            // lane-partial (own 32 keys); partner added at end

#pragma unroll
    for (int i = 0; i < 16; ++i) { ot0[i] *= sc; ot1[i] *= sc; }

    // ---- pack P^T -> bf16 B-frags (cvt_pk + permlane32_swap), then PV ----
    // s reg i (per kb): key = kb*32 + (i&3) + 8*(i>>2) + 4*hi
#pragma unroll
    for (int kb = 0; kb < 2; ++kb) {
      const f32x16& p = kb ? s1 : s0;
      unsigned d0 = cvt_pk(p[0],  p[1]);
      unsigned d2 = cvt_pk(p[4],  p[5]);
      pl32_swap(d0, d2);              // d0: keys hi*8+{0,1}; d2: hi*8+{4,5}
      unsigned d1 = cvt_pk(p[2],  p[3]);
      unsigned d3 = cvt_pk(p[6],  p[7]);
      pl32_swap(d1, d3);
      u32x4 pa0u = {d0, d1, d2, d3};  // keys kb*32 + hi*8 + 0..7
      unsigned e0 = cvt_pk(p[8],  p[9]);
      unsigned e2 = cvt_pk(p[12], p[13]);
      pl32_swap(e0, e2);
      unsigned e1 = cvt_pk(p[10], p[11]);
      unsigned e3 = cvt_pk(p[14], p[15]);
      pl32_swap(e1, e3);
      u32x4 pa1u = {e0, e1, e2, e3};  // keys kb*32 + 16 + hi*8 + 0..7
      short8 pa0 = __builtin_bit_cast(short8, pa0u);
      short8 pa1 = __builtin_bit_cast(short8, pa1u);

      // O^T += V^T P^T : A = VF frag (c2 = kb*2+ks, dt), B = pa[ks]
      short8 v00 = *(const short8*)(lds + 8192 + roff[kb * 2 + 0][0]);
      ot0 = MFMA32(v00, pa0, ot0, 0, 0, 0);
      short8 v01 = *(const short8*)(lds + 8192 + roff[kb * 2 + 0][1]);
      ot1 = MFMA32(v01, pa0, ot1, 0, 0, 0);
      short8 v10 = *(const short8*)(lds + 8192 + roff[kb * 2 + 1][0]);
      ot0 = MFMA32(v10, pa1, ot0, 0, 0, 0);
      short8 v11 = *(const short8*)(lds + 8192 + roff[kb * 2 + 1][1]);
      ot1 = MFMA32(v11, pa1, ot1, 0, 0, 0);
    }
  }

  // ---- normalize + store: O^T reg r -> d = dt*32 + 8*(r>>2) + 4*hi + (r&3) ----
  const float lt  = lsum + __shfl_xor(lsum, 32, 64);
  const float inv = 1.0f / lt;
  const int s_row = qt * 128 + w * 32 + cc;
  float* op = out + ((size_t)(b * 1024 + s_row) << 10) + h * 64;
#pragma unroll
  for (int rg = 0; rg < 4; ++rg) {
    const int d0 = 8 * rg + 4 * hi;
    f32x4 v0, v1;
#pragma unroll
    for (int j = 0; j < 4; ++j) {
      v0[j] = ot0[rg * 4 + j] * inv;
      v1[j] = ot1[rg * 4 + j] * inv;
    }
    *(f32x4*)(op + d0)      = v0;
    *(f32x4*)(op + 32 + d0) = v1;
  }
}

extern "C" void kernel_launch(void* const* d_in, const int* in_sizes, int n_in,
                              void* d_out, int out_size, void* d_ws, size_t ws_size,
                              hipStream_t stream) {
  const float* x  = (const float*)d_in[0];
  const float* Wq = (const float*)d_in[1];
  const float* bq = (const float*)d_in[2];
  const float* Wk = (const float*)d_in[3];
  const float* bk = (const float*)d_in[4];
  const float* Wv = (const float*)d_in[5];
  const float* bv = (const float*)d_in[6];
  float* out = (float*)d_out;

  unsigned short* q_ws  = (unsigned short*)d_ws;
  unsigned short* k_ws  = q_ws + (size_t)8388608;
  unsigned short* vt_ws = k_ws + (size_t)8388608;

  qkv_proj_kernel<<<2048, 256, 0, stream>>>(x, Wq, bq, Wk, bk, Wv, bv,
                                            q_ws, k_ws, vt_ws);
  attn_kernel<<<1024, 256, 0, stream>>>(q_ws, k_ws, vt_ws, out);
}